// Round 1
// baseline (3154.056 us; speedup 1.0000x reference)
//
#include <hip/hip_runtime.h>
#include <math.h>

#define B_ 2
#define T_ 2048
#define D_ 1024
#define H_ 16
#define DH_ 64
#define TD3_ 3072
#define NROWS_ 4096            // B*T
#define BHT_ 65536             // B*H*T

// ---------------- reduction helpers (block = 256 threads, wave = 64) ----------------
__device__ __forceinline__ float wave_sum(float v) {
#pragma unroll
    for (int o = 32; o > 0; o >>= 1) v += __shfl_down(v, o, 64);
    return v;
}
__device__ __forceinline__ float wave_max(float v) {
#pragma unroll
    for (int o = 32; o > 0; o >>= 1) v = fmaxf(v, __shfl_down(v, o, 64));
    return v;
}
__device__ __forceinline__ float block_sum(float v, float* red) {
    v = wave_sum(v);
    __syncthreads();
    if ((threadIdx.x & 63) == 0) red[threadIdx.x >> 6] = v;
    __syncthreads();
    return red[0] + red[1] + red[2] + red[3];
}
__device__ __forceinline__ float block_max(float v, float* red) {
    v = wave_max(v);
    __syncthreads();
    if ((threadIdx.x & 63) == 0) red[threadIdx.x >> 6] = v;
    __syncthreads();
    return fmaxf(fmaxf(red[0], red[1]), fmaxf(red[2], red[3]));
}

// ---------------- LayerNorm: one block per row, D=1024 ----------------
__global__ __launch_bounds__(256)
void ln_kernel(const float* __restrict__ x, const float* __restrict__ g,
               const float* __restrict__ bb, float* __restrict__ out)
{
    __shared__ float red[4];
    const int row = blockIdx.x;
    const float* xr = x + (size_t)row * D_;
    float* orow = out + (size_t)row * D_;
    const int i = threadIdx.x * 4;          // 256*4 = 1024 exactly
    float4 v = *(const float4*)(xr + i);
    float s = v.x + v.y + v.z + v.w;
    float ss = v.x * v.x + v.y * v.y + v.z * v.z + v.w * v.w;
    const float ms = block_sum(s, red);
    const float mss = block_sum(ss, red);
    const float mu = ms * (1.0f / D_);
    const float var = mss * (1.0f / D_) - mu * mu;
    const float inv = rsqrtf(var + 1e-5f);
    float4 gv = *(const float4*)(g + i);
    float4 bv = *(const float4*)(bb + i);
    float4 o;
    o.x = (v.x - mu) * inv * gv.x + bv.x;
    o.y = (v.y - mu) * inv * gv.y + bv.y;
    o.z = (v.z - mu) * inv * gv.z + bv.z;
    o.w = (v.w - mu) * inv * gv.w + bv.w;
    *(float4*)(orow + i) = o;
}

// ---------------- fp32 GEMM: C = A@W (+bias)(+gelu)(+resid), 128x128x16, 8x8/thread ----------------
__global__ __launch_bounds__(256)
void gemm_kernel(const float* __restrict__ A, const float* __restrict__ W,
                 const float* __restrict__ bias, const float* __restrict__ resid,
                 float* __restrict__ C, int M, int N, int K, int do_gelu)
{
    __shared__ float As[16][136];   // [k][m], padded
    __shared__ float Ws[16][136];   // [k][n], padded
    const int tid = threadIdx.x;
    const int m0 = blockIdx.x * 128;
    const int n0 = blockIdx.y * 128;
    const int am = tid >> 1, ak = (tid & 1) << 3;
    const int wk = tid >> 4, wn = (tid & 15) << 3;
    const int tx = tid & 15, ty = tid >> 4;
    float acc[8][8];
#pragma unroll
    for (int i = 0; i < 8; ++i)
#pragma unroll
        for (int j = 0; j < 8; ++j) acc[i][j] = 0.f;

    const float* ap = A + (size_t)(m0 + am) * K + ak;
    const float* wp = W + (size_t)wk * N + n0 + wn;

    for (int k0 = 0; k0 < K; k0 += 16) {
        float4 a0 = *(const float4*)(ap + k0);
        float4 a1 = *(const float4*)(ap + k0 + 4);
        float4 w0 = *(const float4*)(wp + (size_t)k0 * N);
        float4 w1 = *(const float4*)(wp + (size_t)k0 * N + 4);
        As[ak + 0][am] = a0.x; As[ak + 1][am] = a0.y; As[ak + 2][am] = a0.z; As[ak + 3][am] = a0.w;
        As[ak + 4][am] = a1.x; As[ak + 5][am] = a1.y; As[ak + 6][am] = a1.z; As[ak + 7][am] = a1.w;
        *(float4*)&Ws[wk][wn] = w0;
        *(float4*)&Ws[wk][wn + 4] = w1;
        __syncthreads();
#pragma unroll
        for (int k = 0; k < 16; ++k) {
            float4 av0 = *(const float4*)&As[k][ty * 8];
            float4 av1 = *(const float4*)&As[k][ty * 8 + 4];
            float4 wv0 = *(const float4*)&Ws[k][tx * 8];
            float4 wv1 = *(const float4*)&Ws[k][tx * 8 + 4];
            float a[8] = {av0.x, av0.y, av0.z, av0.w, av1.x, av1.y, av1.z, av1.w};
            float w[8] = {wv0.x, wv0.y, wv0.z, wv0.w, wv1.x, wv1.y, wv1.z, wv1.w};
#pragma unroll
            for (int i = 0; i < 8; ++i)
#pragma unroll
                for (int j = 0; j < 8; ++j) acc[i][j] += a[i] * w[j];
        }
        __syncthreads();
    }
    float bi[8];
    if (bias) {
        float4 b0 = *(const float4*)(bias + n0 + tx * 8);
        float4 b1v = *(const float4*)(bias + n0 + tx * 8 + 4);
        bi[0] = b0.x; bi[1] = b0.y; bi[2] = b0.z; bi[3] = b0.w;
        bi[4] = b1v.x; bi[5] = b1v.y; bi[6] = b1v.z; bi[7] = b1v.w;
    } else {
#pragma unroll
        for (int j = 0; j < 8; ++j) bi[j] = 0.f;
    }
#pragma unroll
    for (int i = 0; i < 8; ++i) {
        size_t m = m0 + ty * 8 + i;
        float* crow = C + m * N + n0 + tx * 8;
        float o[8];
#pragma unroll
        for (int j = 0; j < 8; ++j) {
            float v = acc[i][j] + bi[j];
            if (do_gelu) v = 0.5f * v * (1.0f + erff(v * 0.70710678118654752f));
            o[j] = v;
        }
        if (resid) {
            const float* rrow = resid + m * N + n0 + tx * 8;
            float4 r0 = *(const float4*)rrow;
            float4 r1 = *(const float4*)(rrow + 4);
            o[0] += r0.x; o[1] += r0.y; o[2] += r0.z; o[3] += r0.w;
            o[4] += r1.x; o[5] += r1.y; o[6] += r1.z; o[7] += r1.w;
        }
        *(float4*)crow = make_float4(o[0], o[1], o[2], o[3]);
        *(float4*)(crow + 4) = make_float4(o[4], o[5], o[6], o[7]);
    }
}

// ---------------- logits: s = QK^T/8 - dists, 64x64 tiles, causal tiles skipped ----------------
__global__ __launch_bounds__(256)
void logits_kernel(const float* __restrict__ qkv, const float* __restrict__ dists,
                   float* __restrict__ wout)
{
    const int it = blockIdx.x, jt = blockIdx.y;
    if (jt > it) return;
    const int bh = blockIdx.z;
    const int b = bh >> 4, hh = bh & 15;
    const int i0 = it << 6, j0 = jt << 6;
    __shared__ float Qs[64][65];
    __shared__ float Ks[64][65];
    const int tid = threadIdx.x;
    {
        int r = tid >> 2;
        int c0 = (tid & 3) << 4;
        const float* qp = qkv + ((size_t)(b * T_ + i0 + r)) * TD3_ + hh * DH_ + c0;
        const float* kp = qkv + ((size_t)(b * T_ + j0 + r)) * TD3_ + D_ + hh * DH_ + c0;
#pragma unroll
        for (int u = 0; u < 16; u += 4) {
            float4 qa = *(const float4*)(qp + u);
            Qs[r][c0 + u] = qa.x; Qs[r][c0 + u + 1] = qa.y; Qs[r][c0 + u + 2] = qa.z; Qs[r][c0 + u + 3] = qa.w;
            float4 ka = *(const float4*)(kp + u);
            Ks[r][c0 + u] = ka.x; Ks[r][c0 + u + 1] = ka.y; Ks[r][c0 + u + 2] = ka.z; Ks[r][c0 + u + 3] = ka.w;
        }
    }
    __syncthreads();
    const int tx = tid & 15, ty = tid >> 4;
    float acc[4][4] = {};
#pragma unroll 8
    for (int d = 0; d < 64; ++d) {
        float q[4], k[4];
#pragma unroll
        for (int i = 0; i < 4; ++i) q[i] = Qs[ty * 4 + i][d];
#pragma unroll
        for (int j = 0; j < 4; ++j) k[j] = Ks[tx * 4 + j][d];
#pragma unroll
        for (int i = 0; i < 4; ++i)
#pragma unroll
            for (int j = 0; j < 4; ++j) acc[i][j] += q[i] * k[j];
    }
    float* wbase = wout + ((size_t)bh * T_) * T_;
    const float* dbase = dists + ((size_t)b * T_) * T_;
#pragma unroll
    for (int i = 0; i < 4; ++i) {
        int gi = i0 + ty * 4 + i;
#pragma unroll
        for (int j = 0; j < 4; ++j) {
            int gj = j0 + tx * 4 + j;
            if (gj <= gi) {
                wbase[(size_t)gi * T_ + gj] = acc[i][j] * 0.125f - dbase[(size_t)gi * T_ + gj];
            }
        }
    }
}

// ---------------- row softmax (in place on w), zero-fill causal, energy partials ----------------
__global__ __launch_bounds__(256)
void softmax_kernel(float* __restrict__ w, const float* __restrict__ dists,
                    float* __restrict__ parts)
{
    __shared__ float buf[T_];
    __shared__ float red[4];
    const int row = blockIdx.x;             // bh*T + i
    const int i = row & (T_ - 1);
    const int bh = row >> 11;
    const int b = bh >> 4;
    float* wr = w + (size_t)row * T_;
    const float* dr = dists + ((size_t)(b * T_ + i)) * T_;
    const int n = i + 1;
    float lmax = -3.4e38f;
    for (int j = threadIdx.x; j < n; j += 256) {
        float v = wr[j];
        buf[j] = v;
        lmax = fmaxf(lmax, v);
    }
    const float mx = block_max(lmax, red);
    float lsum = 0.f;
    for (int j = threadIdx.x; j < n; j += 256) {
        float e = expf(buf[j] - mx);
        buf[j] = e;
        lsum += e;
    }
    const float S = block_sum(lsum, red);
    const float inv = 1.0f / S;
    float de = 0.f, fe = 0.f;
    for (int j = threadIdx.x; j < n; j += 256) {
        float ww = buf[j] * inv;
        wr[j] = ww;
        de += ww * dr[j];
        fe -= ww * logf(ww + 1e-9f);
    }
    for (int j = n + (int)threadIdx.x; j < T_; j += 256) wr[j] = 0.f;
    de = block_sum(de, red);
    fe = block_sum(fe, red);
    if (threadIdx.x == 0) {
        parts[row] = de;
        parts[BHT_ + row] = fe;
    }
}

// ---------------- attn = w @ v : 32 rows x 64 cols per block, skip zero tiles ----------------
__global__ __launch_bounds__(256)
void attnv_kernel(const float* __restrict__ w, const float* __restrict__ qkv,
                  float* __restrict__ attn)
{
    __shared__ float Wt[32][33];
    __shared__ float Vt[32][64];
    const int it = blockIdx.x;
    const int bh = blockIdx.y;
    const int b = bh >> 4, hh = bh & 15;
    const int tid = threadIdx.x;
    const int d = tid & 63;
    const int ri = tid >> 6;                // wave id: rows ri*8 .. ri*8+7
    const float* wbase = w + ((size_t)bh * T_ + (size_t)it * 32) * T_;
    const float* vbase = qkv + (size_t)b * T_ * TD3_ + 2 * D_ + hh * DH_;
    float acc[8];
#pragma unroll
    for (int r = 0; r < 8; ++r) acc[r] = 0.f;
    const int wr_ = tid >> 3;
    const int wc = (tid & 7) << 2;
    const int vr = tid >> 3, vc = (tid & 7) << 3;
    for (int j0 = 0; j0 <= it * 32; j0 += 32) {
        // w region base is only 8B aligned -> float2 loads
        const float* wsrc = wbase + (size_t)wr_ * T_ + j0 + wc;
        float2 wa = *(const float2*)wsrc;
        float2 wb = *(const float2*)(wsrc + 2);
        Wt[wr_][wc] = wa.x; Wt[wr_][wc + 1] = wa.y; Wt[wr_][wc + 2] = wb.x; Wt[wr_][wc + 3] = wb.y;
        const float* vsrc = vbase + (size_t)(j0 + vr) * TD3_ + vc;
        float4 v0 = *(const float4*)vsrc;
        float4 v1 = *(const float4*)(vsrc + 4);
        Vt[vr][vc] = v0.x; Vt[vr][vc + 1] = v0.y; Vt[vr][vc + 2] = v0.z; Vt[vr][vc + 3] = v0.w;
        Vt[vr][vc + 4] = v1.x; Vt[vr][vc + 5] = v1.y; Vt[vr][vc + 6] = v1.z; Vt[vr][vc + 7] = v1.w;
        __syncthreads();
#pragma unroll 8
        for (int jj = 0; jj < 32; ++jj) {
            float vv = Vt[jj][d];
#pragma unroll
            for (int r = 0; r < 8; ++r)
                acc[r] += Wt[ri * 8 + r][jj] * vv;
        }
        __syncthreads();
    }
#pragma unroll
    for (int r = 0; r < 8; ++r) {
        int gi = it * 32 + ri * 8 + r;
        attn[((size_t)(b * T_ + gi)) * D_ + hh * DH_ + d] = acc[r];
    }
}

// ---------------- stage-2 energy reduction ----------------
__global__ __launch_bounds__(256)
void reduce_energy_kernel(const float* __restrict__ parts, float* __restrict__ out_e)
{
    __shared__ float red[4];
    const float* p = parts + (size_t)blockIdx.y * BHT_ + (size_t)blockIdx.x * 1024;
    float s = 0.f;
    for (int i = threadIdx.x; i < 1024; i += 256) s += p[i];
    s = block_sum(s, red);
    if (threadIdx.x == 0) atomicAdd(&out_e[blockIdx.y], s * (1.0f / BHT_));
}

// ---------------- launch ----------------
extern "C" void kernel_launch(void* const* d_in, const int* in_sizes, int n_in,
                              void* d_out_v, int out_size, void* d_ws, size_t ws_size,
                              hipStream_t stream)
{
    const float* x    = (const float*)d_in[0];
    const float* td   = (const float*)d_in[1];
    const float* ln1g = (const float*)d_in[2];
    const float* ln1b = (const float*)d_in[3];
    const float* wqkv = (const float*)d_in[4];
    const float* wproj= (const float*)d_in[5];
    const float* ln2g = (const float*)d_in[6];
    const float* ln2b = (const float*)d_in[7];
    const float* w1   = (const float*)d_in[8];
    const float* b1   = (const float*)d_in[9];
    const float* w2   = (const float*)d_in[10];
    const float* b2   = (const float*)d_in[11];
    float* out = (float*)d_out_v;

    // output layout: x (4194304) | dist_e (1) | flop_e (1) | w (134217728) | token_dists (8388608)
    float* out_x  = out;
    float* out_e  = out + 4194304;
    float* out_w  = out + 4194306;
    float* out_td = out + 138412034;

    float* ws    = (float*)d_ws;
    float* h     = ws;                                       // 4194304
    float* qkv   = h    + (size_t)NROWS_ * D_;               // 12582912
    float* attn  = qkv  + (size_t)NROWS_ * TD3_;             // 4194304
    float* x1    = attn + (size_t)NROWS_ * D_;               // 4194304
    float* h2    = x1   + (size_t)NROWS_ * D_;               // 4194304
    float* ffn1  = h2   + (size_t)NROWS_ * D_;               // 16777216
    float* parts = ffn1 + (size_t)NROWS_ * 4 * D_;           // 131072

    hipMemsetAsync(out_e, 0, 2 * sizeof(float), stream);

    ln_kernel<<<NROWS_, 256, 0, stream>>>(x, ln1g, ln1b, h);

    dim3 gq(NROWS_ / 128, TD3_ / 128);
    gemm_kernel<<<gq, 256, 0, stream>>>(h, wqkv, nullptr, nullptr, qkv, NROWS_, TD3_, D_, 0);

    dim3 gl(T_ / 64, T_ / 64, B_ * H_);
    logits_kernel<<<gl, 256, 0, stream>>>(qkv, td, out_w);

    softmax_kernel<<<BHT_, 256, 0, stream>>>(out_w, td, parts);

    dim3 ga(T_ / 32, B_ * H_);
    attnv_kernel<<<ga, 256, 0, stream>>>(out_w, qkv, attn);

    dim3 gp(NROWS_ / 128, D_ / 128);
    gemm_kernel<<<gp, 256, 0, stream>>>(attn, wproj, nullptr, x, x1, NROWS_, D_, D_, 0);

    ln_kernel<<<NROWS_, 256, 0, stream>>>(x1, ln2g, ln2b, h2);

    dim3 gf1(NROWS_ / 128, (4 * D_) / 128);
    gemm_kernel<<<gf1, 256, 0, stream>>>(h2, w1, b1, nullptr, ffn1, NROWS_, 4 * D_, D_, 1);

    dim3 gf2(NROWS_ / 128, D_ / 128);
    gemm_kernel<<<gf2, 256, 0, stream>>>(ffn1, w2, b2, x1, out_x, NROWS_, D_, 4 * D_, 0);

    reduce_energy_kernel<<<dim3(64, 2), 256, 0, stream>>>(parts, out_e);

    hipMemcpyAsync(out_td, td, (size_t)B_ * T_ * T_ * sizeof(float),
                   hipMemcpyDeviceToDevice, stream);
}

// Round 2
// 2016.320 us; speedup vs baseline: 1.5643x; 1.5643x over previous
//
#include <hip/hip_runtime.h>
#include <math.h>

#define B_ 2
#define T_ 2048
#define D_ 1024
#define H_ 16
#define DH_ 64
#define TD3_ 3072
#define NROWS_ 4096            // B*T
#define BHT_ 65536             // B*H*T

typedef __attribute__((ext_vector_type(4))) float floatx4;
typedef __attribute__((ext_vector_type(8))) short short8;

__device__ __forceinline__ unsigned short f2bf(float x) {
    union { float f; unsigned u; } c; c.f = x;
    unsigned r = c.u + 0x7FFF + ((c.u >> 16) & 1);
    return (unsigned short)(r >> 16);
}

// async global->LDS, 16B per lane; LDS dest = wave-uniform base + lane*16
__device__ __forceinline__ void gload_lds16(const void* g, void* lds) {
    __builtin_amdgcn_global_load_lds(
        (const __attribute__((address_space(1))) unsigned int*)(unsigned long long)(uintptr_t)g,
        (__attribute__((address_space(3))) unsigned int*)(unsigned int)(uintptr_t)lds,
        16, 0, 0);
}

// ---------------- reduction helpers ----------------
__device__ __forceinline__ float wave_sum(float v) {
#pragma unroll
    for (int o = 32; o > 0; o >>= 1) v += __shfl_down(v, o, 64);
    return v;
}
__device__ __forceinline__ float wave_max(float v) {
#pragma unroll
    for (int o = 32; o > 0; o >>= 1) v = fmaxf(v, __shfl_down(v, o, 64));
    return v;
}
__device__ __forceinline__ float block_sum(float v, float* red) {
    v = wave_sum(v);
    __syncthreads();
    if ((threadIdx.x & 63) == 0) red[threadIdx.x >> 6] = v;
    __syncthreads();
    return red[0] + red[1] + red[2] + red[3];
}
__device__ __forceinline__ float block_max(float v, float* red) {
    v = wave_max(v);
    __syncthreads();
    if ((threadIdx.x & 63) == 0) red[threadIdx.x >> 6] = v;
    __syncthreads();
    return fmaxf(fmaxf(red[0], red[1]), fmaxf(red[2], red[3]));
}

// ---------------- LayerNorm -> bf16 out ----------------
__global__ __launch_bounds__(256)
void ln_bf16_kernel(const float* __restrict__ x, const float* __restrict__ g,
                    const float* __restrict__ bb, unsigned short* __restrict__ out)
{
    __shared__ float red[4];
    const int row = blockIdx.x;
    const float* xr = x + (size_t)row * D_;
    unsigned short* orow = out + (size_t)row * D_;
    const int i = threadIdx.x * 4;
    float4 v = *(const float4*)(xr + i);
    float s = v.x + v.y + v.z + v.w;
    float ss = v.x * v.x + v.y * v.y + v.z * v.z + v.w * v.w;
    const float ms = block_sum(s, red);
    const float mss = block_sum(ss, red);
    const float mu = ms * (1.0f / D_);
    const float var = mss * (1.0f / D_) - mu * mu;
    const float inv = rsqrtf(var + 1e-5f);
    float4 gv = *(const float4*)(g + i);
    float4 bv = *(const float4*)(bb + i);
    ushort4 o;
    o.x = f2bf((v.x - mu) * inv * gv.x + bv.x);
    o.y = f2bf((v.y - mu) * inv * gv.y + bv.y);
    o.z = f2bf((v.z - mu) * inv * gv.z + bv.z);
    o.w = f2bf((v.w - mu) * inv * gv.w + bv.w);
    *(ushort4*)(orow + i) = o;
}

// ---------------- weight transpose + fp32->bf16: W[K][N] -> Wt[N][K] ----------------
__global__ __launch_bounds__(256)
void transpose_bf16_kernel(const float* __restrict__ W, unsigned short* __restrict__ Wt,
                           int K, int N)
{
    __shared__ unsigned short tile[32][33];
    const int n0 = blockIdx.x * 32, k0 = blockIdx.y * 32;
    const int tx = threadIdx.x & 31, ty = threadIdx.x >> 5;   // 32 x 8
#pragma unroll
    for (int r = 0; r < 32; r += 8)
        tile[tx][ty + r] = f2bf(W[(size_t)(k0 + ty + r) * N + n0 + tx]);
    __syncthreads();
#pragma unroll
    for (int r = 0; r < 32; r += 8)
        Wt[(size_t)(n0 + ty + r) * K + k0 + tx] = tile[ty + r][tx];
}

// ---------------- bf16 MFMA GEMM (m97 structure): C = A[M][K] @ Bt[N][K]^T ----------------
template<int OUT_BF16, int DO_GELU, int HAS_BIAS, int HAS_RESID>
__global__ __launch_bounds__(256)
void gemm_bt_kernel(const unsigned short* __restrict__ A,
                    const unsigned short* __restrict__ Bt,
                    const float* __restrict__ bias,
                    const float* __restrict__ resid,
                    void* __restrict__ Cv,
                    int M, int N, int K)
{
    __shared__ __align__(16) unsigned short As[128 * 32];   // [m][k] 8KB
    __shared__ __align__(16) unsigned short Bs[128 * 32];   // [n][k] 8KB
    const int tid = threadIdx.x;
    const int wave = tid >> 6;
    const int lane = tid & 63;
    const int m0 = blockIdx.x * 128;
    const int n0 = blockIdx.y * 128;
    const int wm = (wave & 1) * 64;
    const int wn = (wave >> 1) * 64;

    floatx4 acc[4][4];
#pragma unroll
    for (int i = 0; i < 4; ++i)
#pragma unroll
        for (int j = 0; j < 4; ++j) acc[i][j] = (floatx4){0.f, 0.f, 0.f, 0.f};

    // staging: wave w covers tile rows [32w, 32w+32) via 2 issues of 16 rows
    const int srow = lane >> 2;             // 0..15
    const int skoff = (lane & 3) * 8;       // bf16 elems within the 32-wide k-slab
    const unsigned short* Ag = A + (size_t)(m0 + 32 * wave + srow) * K + skoff;
    const unsigned short* Bg = Bt + (size_t)(n0 + 32 * wave + srow) * K + skoff;
    unsigned short* AsW = As + 1024 * wave;
    unsigned short* BsW = Bs + 1024 * wave;

    const int frow = lane & 15;
    const int fk = (lane >> 4) * 8;

    for (int k0 = 0; k0 < K; k0 += 32) {
        gload_lds16(Ag + k0, AsW);
        gload_lds16(Ag + (size_t)16 * K + k0, AsW + 512);
        gload_lds16(Bg + k0, BsW);
        gload_lds16(Bg + (size_t)16 * K + k0, BsW + 512);
        __syncthreads();
        short8 af[4], bfv[4];
#pragma unroll
        for (int mi = 0; mi < 4; ++mi)
            af[mi] = *(const short8*)&As[(wm + mi * 16 + frow) * 32 + fk];
#pragma unroll
        for (int ni = 0; ni < 4; ++ni)
            bfv[ni] = *(const short8*)&Bs[(wn + ni * 16 + frow) * 32 + fk];
#pragma unroll
        for (int mi = 0; mi < 4; ++mi)
#pragma unroll
            for (int ni = 0; ni < 4; ++ni)
                acc[mi][ni] = __builtin_amdgcn_mfma_f32_16x16x32_bf16(
                    af[mi], bfv[ni], acc[mi][ni], 0, 0, 0);
        __syncthreads();
    }

    // epilogue: C/D layout col=lane&15, row=(lane>>4)*4+reg
#pragma unroll
    for (int ni = 0; ni < 4; ++ni) {
        const int col = n0 + wn + ni * 16 + (lane & 15);
        const float bv = HAS_BIAS ? bias[col] : 0.f;
#pragma unroll
        for (int mi = 0; mi < 4; ++mi) {
#pragma unroll
            for (int r = 0; r < 4; ++r) {
                const int row = m0 + wm + mi * 16 + (lane >> 4) * 4 + r;
                float v = acc[mi][ni][r] + bv;
                if (DO_GELU) v = 0.5f * v * (1.0f + erff(v * 0.70710678118654752f));
                if (HAS_RESID) v += resid[(size_t)row * N + col];
                if (OUT_BF16) ((unsigned short*)Cv)[(size_t)row * N + col] = f2bf(v);
                else          ((float*)Cv)[(size_t)row * N + col] = v;
            }
        }
    }
}

// ---------------- logits: s = QK^T/8 - dists, 64x64 tiles, causal skipped (fp32) ----------------
__global__ __launch_bounds__(256)
void logits_kernel(const float* __restrict__ qkv, const float* __restrict__ dists,
                   float* __restrict__ wout)
{
    const int it = blockIdx.x, jt = blockIdx.y;
    if (jt > it) return;
    const int bh = blockIdx.z;
    const int b = bh >> 4, hh = bh & 15;
    const int i0 = it << 6, j0 = jt << 6;
    __shared__ float Qs[64][65];
    __shared__ float Ks[64][65];
    const int tid = threadIdx.x;
    {
        int r = tid >> 2;
        int c0 = (tid & 3) << 4;
        const float* qp = qkv + ((size_t)(b * T_ + i0 + r)) * TD3_ + hh * DH_ + c0;
        const float* kp = qkv + ((size_t)(b * T_ + j0 + r)) * TD3_ + D_ + hh * DH_ + c0;
#pragma unroll
        for (int u = 0; u < 16; u += 4) {
            float4 qa = *(const float4*)(qp + u);
            Qs[r][c0 + u] = qa.x; Qs[r][c0 + u + 1] = qa.y; Qs[r][c0 + u + 2] = qa.z; Qs[r][c0 + u + 3] = qa.w;
            float4 ka = *(const float4*)(kp + u);
            Ks[r][c0 + u] = ka.x; Ks[r][c0 + u + 1] = ka.y; Ks[r][c0 + u + 2] = ka.z; Ks[r][c0 + u + 3] = ka.w;
        }
    }
    __syncthreads();
    const int tx = tid & 15, ty = tid >> 4;
    float acc[4][4] = {};
#pragma unroll 8
    for (int d = 0; d < 64; ++d) {
        float q[4], k[4];
#pragma unroll
        for (int i = 0; i < 4; ++i) q[i] = Qs[ty * 4 + i][d];
#pragma unroll
        for (int j = 0; j < 4; ++j) k[j] = Ks[tx * 4 + j][d];
#pragma unroll
        for (int i = 0; i < 4; ++i)
#pragma unroll
            for (int j = 0; j < 4; ++j) acc[i][j] += q[i] * k[j];
    }
    float* wbase = wout + ((size_t)bh * T_) * T_;
    const float* dbase = dists + ((size_t)b * T_) * T_;
#pragma unroll
    for (int i = 0; i < 4; ++i) {
        int gi = i0 + ty * 4 + i;
#pragma unroll
        for (int j = 0; j < 4; ++j) {
            int gj = j0 + tx * 4 + j;
            if (gj <= gi) {
                wbase[(size_t)gi * T_ + gj] = acc[i][j] * 0.125f - dbase[(size_t)gi * T_ + gj];
            }
        }
    }
}

// ---------------- row softmax (in place on w), zero-fill causal, energy partials ----------------
__global__ __launch_bounds__(256)
void softmax_kernel(float* __restrict__ w, const float* __restrict__ dists,
                    float* __restrict__ parts)
{
    __shared__ float buf[T_];
    __shared__ float red[4];
    const int row = blockIdx.x;             // bh*T + i
    const int i = row & (T_ - 1);
    const int bh = row >> 11;
    const int b = bh >> 4;
    float* wr = w + (size_t)row * T_;
    const float* dr = dists + ((size_t)(b * T_ + i)) * T_;
    const int n = i + 1;
    float lmax = -3.4e38f;
    for (int j = threadIdx.x; j < n; j += 256) {
        float v = wr[j];
        buf[j] = v;
        lmax = fmaxf(lmax, v);
    }
    const float mx = block_max(lmax, red);
    float lsum = 0.f;
    for (int j = threadIdx.x; j < n; j += 256) {
        float e = expf(buf[j] - mx);
        buf[j] = e;
        lsum += e;
    }
    const float S = block_sum(lsum, red);
    const float inv = 1.0f / S;
    float de = 0.f, fe = 0.f;
    for (int j = threadIdx.x; j < n; j += 256) {
        float ww = buf[j] * inv;
        wr[j] = ww;
        de += ww * dr[j];
        fe -= ww * logf(ww + 1e-9f);
    }
    for (int j = n + (int)threadIdx.x; j < T_; j += 256) wr[j] = 0.f;
    de = block_sum(de, red);
    fe = block_sum(fe, red);
    if (threadIdx.x == 0) {
        parts[row] = de;
        parts[BHT_ + row] = fe;
    }
}

// ---------------- attn = w @ v : 32 rows x 64 cols per block, bf16 out ----------------
__global__ __launch_bounds__(256)
void attnv_kernel(const float* __restrict__ w, const float* __restrict__ qkv,
                  unsigned short* __restrict__ attn)
{
    __shared__ float Wt[32][33];
    __shared__ float Vt[32][64];
    const int it = blockIdx.x;
    const int bh = blockIdx.y;
    const int b = bh >> 4, hh = bh & 15;
    const int tid = threadIdx.x;
    const int d = tid & 63;
    const int ri = tid >> 6;
    const float* wbase = w + ((size_t)bh * T_ + (size_t)it * 32) * T_;
    const float* vbase = qkv + (size_t)b * T_ * TD3_ + 2 * D_ + hh * DH_;
    float acc[8];
#pragma unroll
    for (int r = 0; r < 8; ++r) acc[r] = 0.f;
    const int wr_ = tid >> 3;
    const int wc = (tid & 7) << 2;
    const int vr = tid >> 3, vc = (tid & 7) << 3;
    for (int j0 = 0; j0 <= it * 32; j0 += 32) {
        const float* wsrc = wbase + (size_t)wr_ * T_ + j0 + wc;
        float2 wa = *(const float2*)wsrc;
        float2 wb = *(const float2*)(wsrc + 2);
        Wt[wr_][wc] = wa.x; Wt[wr_][wc + 1] = wa.y; Wt[wr_][wc + 2] = wb.x; Wt[wr_][wc + 3] = wb.y;
        const float* vsrc = vbase + (size_t)(j0 + vr) * TD3_ + vc;
        float4 v0 = *(const float4*)vsrc;
        float4 v1 = *(const float4*)(vsrc + 4);
        Vt[vr][vc] = v0.x; Vt[vr][vc + 1] = v0.y; Vt[vr][vc + 2] = v0.z; Vt[vr][vc + 3] = v0.w;
        Vt[vr][vc + 4] = v1.x; Vt[vr][vc + 5] = v1.y; Vt[vr][vc + 6] = v1.z; Vt[vr][vc + 7] = v1.w;
        __syncthreads();
#pragma unroll 8
        for (int jj = 0; jj < 32; ++jj) {
            float vv = Vt[jj][d];
#pragma unroll
            for (int r = 0; r < 8; ++r)
                acc[r] += Wt[ri * 8 + r][jj] * vv;
        }
        __syncthreads();
    }
#pragma unroll
    for (int r = 0; r < 8; ++r) {
        int gi = it * 32 + ri * 8 + r;
        attn[((size_t)(b * T_ + gi)) * D_ + hh * DH_ + d] = f2bf(acc[r]);
    }
}

// ---------------- stage-2 energy reduction ----------------
__global__ __launch_bounds__(256)
void reduce_energy_kernel(const float* __restrict__ parts, float* __restrict__ out_e)
{
    __shared__ float red[4];
    const float* p = parts + (size_t)blockIdx.y * BHT_ + (size_t)blockIdx.x * 1024;
    float s = 0.f;
    for (int i = threadIdx.x; i < 1024; i += 256) s += p[i];
    s = block_sum(s, red);
    if (threadIdx.x == 0) atomicAdd(&out_e[blockIdx.y], s * (1.0f / BHT_));
}

// ---------------- launch ----------------
extern "C" void kernel_launch(void* const* d_in, const int* in_sizes, int n_in,
                              void* d_out_v, int out_size, void* d_ws, size_t ws_size,
                              hipStream_t stream)
{
    const float* x    = (const float*)d_in[0];
    const float* td   = (const float*)d_in[1];
    const float* ln1g = (const float*)d_in[2];
    const float* ln1b = (const float*)d_in[3];
    const float* wqkv = (const float*)d_in[4];
    const float* wproj= (const float*)d_in[5];
    const float* ln2g = (const float*)d_in[6];
    const float* ln2b = (const float*)d_in[7];
    const float* w1   = (const float*)d_in[8];
    const float* b1   = (const float*)d_in[9];
    const float* w2   = (const float*)d_in[10];
    const float* b2   = (const float*)d_in[11];
    float* out = (float*)d_out_v;

    // output layout: x (4194304) | dist_e (1) | flop_e (1) | w (134217728) | token_dists (8388608)
    float* out_x  = out;
    float* out_e  = out + 4194304;
    float* out_w  = out + 4194306;
    float* out_td = out + 138412034;

    char* p = (char*)d_ws;
    float* qkv   = (float*)p;              p += (size_t)NROWS_ * TD3_ * 4;   // fp32, 48MB
    float* x1    = (float*)p;              p += (size_t)NROWS_ * D_ * 4;     // 16MB
    float* parts = (float*)p;              p += (size_t)2 * BHT_ * 4;        // 0.5MB
    unsigned short* hb    = (unsigned short*)p; p += (size_t)NROWS_ * D_ * 2;        // 8MB
    unsigned short* attnb = (unsigned short*)p; p += (size_t)NROWS_ * D_ * 2;        // 8MB
    unsigned short* h2b   = (unsigned short*)p; p += (size_t)NROWS_ * D_ * 2;        // 8MB
    unsigned short* ffn1b = (unsigned short*)p; p += (size_t)NROWS_ * 4 * D_ * 2;    // 32MB
    unsigned short* wqkvT = (unsigned short*)p; p += (size_t)TD3_ * D_ * 2;          // 6MB
    unsigned short* wprojT= (unsigned short*)p; p += (size_t)D_ * D_ * 2;            // 2MB
    unsigned short* w1T   = (unsigned short*)p; p += (size_t)4 * D_ * D_ * 2;        // 8MB
    unsigned short* w2T   = (unsigned short*)p; p += (size_t)4 * D_ * D_ * 2;        // 8MB

    hipMemsetAsync(out_e, 0, 2 * sizeof(float), stream);

    // weight transposes (fp32 [K][N] -> bf16 [N][K])
    transpose_bf16_kernel<<<dim3(TD3_ / 32, D_ / 32), 256, 0, stream>>>(wqkv, wqkvT, D_, TD3_);
    transpose_bf16_kernel<<<dim3(D_ / 32, D_ / 32), 256, 0, stream>>>(wproj, wprojT, D_, D_);
    transpose_bf16_kernel<<<dim3(4 * D_ / 32, D_ / 32), 256, 0, stream>>>(w1, w1T, D_, 4 * D_);
    transpose_bf16_kernel<<<dim3(D_ / 32, 4 * D_ / 32), 256, 0, stream>>>(w2, w2T, 4 * D_, D_);

    ln_bf16_kernel<<<NROWS_, 256, 0, stream>>>(x, ln1g, ln1b, hb);

    gemm_bt_kernel<0, 0, 0, 0><<<dim3(NROWS_ / 128, TD3_ / 128), 256, 0, stream>>>(
        hb, wqkvT, nullptr, nullptr, qkv, NROWS_, TD3_, D_);

    dim3 gl(T_ / 64, T_ / 64, B_ * H_);
    logits_kernel<<<gl, 256, 0, stream>>>(qkv, td, out_w);

    softmax_kernel<<<BHT_, 256, 0, stream>>>(out_w, td, parts);

    dim3 ga(T_ / 32, B_ * H_);
    attnv_kernel<<<ga, 256, 0, stream>>>(out_w, qkv, attnb);

    gemm_bt_kernel<0, 0, 0, 1><<<dim3(NROWS_ / 128, D_ / 128), 256, 0, stream>>>(
        attnb, wprojT, nullptr, x, x1, NROWS_, D_, D_);

    ln_bf16_kernel<<<NROWS_, 256, 0, stream>>>(x1, ln2g, ln2b, h2b);

    gemm_bt_kernel<1, 1, 1, 0><<<dim3(NROWS_ / 128, 4 * D_ / 128), 256, 0, stream>>>(
        h2b, w1T, b1, nullptr, ffn1b, NROWS_, 4 * D_, D_);

    gemm_bt_kernel<0, 0, 1, 1><<<dim3(NROWS_ / 128, D_ / 128), 256, 0, stream>>>(
        ffn1b, w2T, b2, x1, out_x, NROWS_, D_, 4 * D_);

    reduce_energy_kernel<<<dim3(64, 2), 256, 0, stream>>>(parts, out_e);

    hipMemcpyAsync(out_td, td, (size_t)B_ * T_ * T_ * sizeof(float),
                   hipMemcpyDeviceToDevice, stream);
}